// Round 10
// baseline (320.560 us; speedup 1.0000x reference)
//
#include <hip/hip_runtime.h>
#include <hip/hip_bf16.h>

// FastUpConvolution on MI355X — round 17: panel-pair fused gemm blocks.
// One block per (bm, n-pair) computes BOTH the P0 (even-output-row) and P1
// (odd-row) 128-n panels over the same 128 m as a flat pipeline of 15
// W-tiles (t0P0,t0P1,...,t5P1,t6P0,t7P0,t8P0) through R16's PROVEN
// triple-buffer / prefetch-2 / fused-{vmcnt(4) lgkmcnt(0); s_barrier}
// discipline (sync structure unchanged — only the tile list differs).
//
// R16 post-mortem: pipeline passed but bought only ~5us (148.9->144;
// MfmaUtil 38.5) -> barrier drain was NOT the main stall. LDS-port demand
// (~75us frag reads + ~15us DMA writes) is the binding resource, and the
// structural waste is X being staged twice per m-block (P0 block + P1
// block). Fusing the pair: X staged once (-45% X DMA, prologue drains
// halved), 512 identical blocks = exactly 2/CU (no tap imbalance, flip
// deleted), each XCD pinned to one n-pair (W 2.25MB L2-resident), BN
// atomics halved. acc doubles to 128 VGPR (~190-220 total; failure
// signature: VGPR>=256 + regression).
//
// ws layout:
//   x_t   : bf16 [16][34][34][512]  @ 0          (18,939,904 B)
//   W_t   : bf16 [1024 rows][9*512] @ 18,939,904 ( 9,437,184 B)  row=pair-ilv
//   bias  : f32  [1024]             @ 28,377,088 (     4,096 B)  row=pair-ilv
//   stats : f32  [512] sum|sumsq    @ 28,381,184 (     2,048 B)
//
// Row layout: row' = ((q&1)<<9) + co*2 + (q>>1):
//   P0 rows 0..511   : q0 (3x3) s=0, q2 (3x2) s=1  -> even output rows, 9 taps
//   P1 rows 512..1023: q1 (2x3) s=0, q3 (2x2) s=1  -> odd output rows, 6 taps

typedef unsigned short ushort_t;
typedef __attribute__((ext_vector_type(8))) short short8;
typedef __attribute__((ext_vector_type(4))) float floatx4;
typedef __attribute__((ext_vector_type(2))) float floatx2;
typedef __attribute__((ext_vector_type(4))) unsigned short u16x4;
typedef __attribute__((ext_vector_type(8))) unsigned short u16x8;
typedef __attribute__((ext_vector_type(4))) unsigned int u32x4;

#define XT_OFF    0u
#define WT_OFF    18939904u
#define BIAS_OFF  28377088u
#define STATS_OFF 28381184u

#define NSITES 204            // 6 rows x 34 cols X footprint, 128 B per site
#define WPAN   4718592u       // P1 panel byte offset in W_t (512 rows x 9216)

#define ASYNC16(g, l) __builtin_amdgcn_global_load_lds( \
    (const __attribute__((address_space(1))) void*)(g), \
    (__attribute__((address_space(3))) void*)(l), 16, 0, 0)

// Zero-instruction compiler fence: pins emission order of memory intrinsics
// (vmcnt counts in emission order; counted waits depend on it).
#define ISSUE_FENCE asm volatile("" ::: "memory")

// Fused wait+barrier (R16-proven). vmcnt(4): newest W-tile prefetch stays in
// flight. lgkmcnt(0): all own LDS reads returned before the barrier (no WAR
// vs the next segment's DMA into the recycled buffer).
#define WAITBAR4 \
  asm volatile("s_waitcnt vmcnt(4) lgkmcnt(0)\n\ts_barrier" ::: "memory")
#define WAITBAR0 \
  asm volatile("s_waitcnt vmcnt(0) lgkmcnt(0)\n\ts_barrier" ::: "memory")

__device__ __forceinline__ ushort_t f2bf(float f) {
  unsigned int u = __builtin_bit_cast(unsigned int, f);
  u += 0x7fffu + ((u >> 16) & 1u);   // RNE (values finite here)
  return (ushort_t)(u >> 16);
}

// --------------------------------------------------------------- prep_all --
// Blocks 0..1023: W prep. W_t[row'][tap][ci] bf16, invalid taps zero-filled;
//   block 0 also zeroes stats. Blocks 1024..1567: x[16][512][32][32] f32 ->
//   x_t[16][34][34][512] bf16, zero-padded NHWC.
__global__ __launch_bounds__(256) void prep_all(
    const float* __restrict__ x, ushort_t* __restrict__ xt,
    const float* __restrict__ w1, const float* __restrict__ w2,
    const float* __restrict__ w3, const float* __restrict__ w4,
    const float* __restrict__ b1, const float* __restrict__ b2,
    const float* __restrict__ b3, const float* __restrict__ b4,
    ushort_t* __restrict__ wt, float* __restrict__ bias,
    float* __restrict__ stats) {
  __shared__ ushort_t lds[128 * 36];
  const int blk = blockIdx.x;
  const int t = threadIdx.x;
  if (blk < 1024) {
    // ---------------- W prep ----------------
    const int q = blk >> 8, co = blk & 255;
    const int row = ((q & 1) << 9) + (co << 1) + (q >> 1);  // pair-interleaved
    if (blk == 0) { stats[t] = 0.f; stats[t + 256] = 0.f; }
    const float* wsrc; const float* bsrc; int khl, kwl;
    if (q == 0)      { wsrc = w1; bsrc = b1; khl = 3; kwl = 3; }
    else if (q == 1) { wsrc = w2; bsrc = b2; khl = 2; kwl = 3; }
    else if (q == 2) { wsrc = w3; bsrc = b3; khl = 3; kwl = 2; }
    else             { wsrc = w4; bsrc = b4; khl = 2; kwl = 2; }
    if (t == 0) bias[row] = bsrc[co];
    ushort_t* dst = wt + (size_t)row * 4608;
    for (int tap = 0; tap < 9; ++tap) {
      const int dh = tap / 3, dw = tap % 3;
      const bool valid = (dh < khl) && (dw < kwl);
#pragma unroll
      for (int cc = 0; cc < 2; ++cc) {
        const int ci = cc * 256 + t;
        ushort_t v = 0;
        if (valid)
          v = f2bf(wsrc[(((size_t)co * 512 + ci) * khl + dh) * kwl + dw]);
        dst[tap * 512 + ci] = v;
      }
    }
    return;
  }
  // ---------------- X prep ----------------
  const int b = blk - 1024;
  const int n = b / 34, hp = b % 34;
  ushort_t* dst = xt + (size_t)(n * 34 + hp) * (34 * 512);
  if (hp == 0 || hp == 33) {
    u32x4 z = {0u, 0u, 0u, 0u};
    for (int i = t; i < 2176; i += 256) ((u32x4*)dst)[i] = z;
    return;
  }
  const int h = hp - 1;
  {
    u32x4 z = {0u, 0u, 0u, 0u};
    if (t < 64) ((u32x4*)dst)[t] = z;
    else if (t < 128) ((u32x4*)(dst + 33 * 512))[t - 64] = z;
  }
  const size_t base = (size_t)n * 524288 + (size_t)h * 32;
  for (int ci0 = 0; ci0 < 512; ci0 += 128) {
    __syncthreads();
    {
      const int cil = t >> 3;
      const int w4 = (t & 7) << 2;
#pragma unroll
      for (int cc = 0; cc < 4; ++cc) {
        const int ci = cil + cc * 32;
        floatx4 v = *(const floatx4*)(x + base + (size_t)(ci0 + ci) * 1024 + w4);
        u16x4 hv;
#pragma unroll
        for (int j = 0; j < 4; ++j) hv[j] = f2bf(v[j]);
        *(u16x4*)&lds[ci * 36 + w4] = hv;
      }
    }
    __syncthreads();
    {
      const int w = t & 31;
      const int j8 = t >> 5;
#pragma unroll
      for (int cc2 = 0; cc2 < 2; ++cc2) {
        const int cil = cc2 * 64 + j8 * 8;
        u16x8 v;
#pragma unroll
        for (int j = 0; j < 8; ++j) v[j] = lds[(cil + j) * 36 + w];
        *(u16x8*)(dst + (w + 1) * 512 + ci0 + cil) = v;
      }
    }
  }
}

// ------------------------------------------------------------- mfma_seg ----
// One W-tile segment: 2 k-steps x (4 A-frag reads from the tile buffer,
// 4 B-frag reads from swizzled ldsX at tap offset, 16 MFMA) into acc.
__device__ __forceinline__ void mfma_seg(
    const char* wb, const char* ldsX, const int (&arow)[4],
    const int (&bsite)[4], int tsite, int kg, floatx4 (&acc)[4][4]) {
#pragma unroll
  for (int ks = 0; ks < 2; ++ks) {
    const int c = (ks << 2) + kg;      // 16B chunk index within row
    short8 a4[4], b4[4];
#pragma unroll
    for (int f = 0; f < 4; ++f)
      a4[f] = *(const short8*)(wb + arow[f] * 128 +
                               ((c ^ (arow[f] & 7)) << 4));
#pragma unroll
    for (int fj = 0; fj < 4; ++fj) {
      const int srow = bsite[fj] + tsite;   // shifted site; swizzle on it
      b4[fj] = *(const short8*)(ldsX + srow * 128 + ((c ^ (srow & 7)) << 4));
    }
#pragma unroll
    for (int fi = 0; fi < 4; ++fi)
#pragma unroll
      for (int fj = 0; fj < 4; ++fj)
        acc[fi][fj] = __builtin_amdgcn_mfma_f32_16x16x32_bf16(
            a4[fi], b4[fj], acc[fi][fj], 0, 0, 0);
  }
}

// ------------------------------------------------------------------ gemm ---
// Block = 128 m (4h x 32w) x 256 n (one n-PAIR: P0 panel + P1 panel).
// 4 waves 2x2 (64m x 64n per wave per panel), accA/accB 4x4 frags each.
// K = 8 chunks x 64 ci x 15 W-tiles (t0P0,t0P1,..,t5P1,t6P0,t7P0,t8P0).
// Per chunk: stage X once | fence | tile0 | fence | tile1 | WAITBAR4.
// Per tile i: issue tile i+2 -> buf[(i+2)%3]; 32 MFMA on buf[i%3] into
// accA/accB (static per unrolled i); WAITBAR4 (WAITBAR0 for last two).
// LDS unpadded, XOR-swizzled: 16B chunk c of row r at slot c^(r&7).
__global__ __launch_bounds__(256) void gemm_kernel(
    const ushort_t* __restrict__ xt, const ushort_t* __restrict__ wt,
    const float* __restrict__ bias, float* __restrict__ out,
    float* __restrict__ stats) {
  __shared__ char ldsX[NSITES * 128];   // 26,112 B
  __shared__ char ldsW[3][128 * 128];   // 3 x 16,384 B (tile triple buffer)
  const int tid = threadIdx.x;
  const int bx = blockIdx.x;            // 512 blocks = 2/CU, all equal cost
  const int bn2 = bx & 3;               // n-pair (XCD-pinned: bx&7 fixes it)
  const int bm = bx >> 2;               // 0..127
  const int n0 = bn2 << 7;              // P0 row base (P1 = +512 rows)
  const int n_img = bm >> 3;
  const int h0p = (bm & 7) << 2;        // first padded x_t row of footprint
  const int wv = tid >> 6, lane = tid & 63;
  const int ri = lane & 15, kg = lane >> 4;
  const int wm = (wv & 1) << 6, wn = (wv >> 1) << 6;

  // ---- staging pointer precompute (XOR swizzle at issue) ----
  // X: idx = p*256+tid over 1632 = 204 sites x 8 slots.
  const char* xgp[7];
  char* xlp[7];
  {
    const char* xg = (const char*)(xt + (size_t)(n_img * 34 + h0p) * (34 * 512));
#pragma unroll
    for (int p = 0; p < 7; ++p) {
      const int idx = p * 256 + tid;
      const int site = idx >> 3, slot = idx & 7;
      const int c = slot ^ (site & 7);
      xgp[p] = xg + site * 1024 + (c << 4);
      xlp[p] = ldsX + idx * 16;
    }
  }
  // W: idx = p*256+tid over 1024 = 128 rows x 8 slots (P0 base; +WPAN = P1).
  const char* wgp[4];
#pragma unroll
  for (int p = 0; p < 4; ++p) {
    const int idx = p * 256 + tid;
    const int row = idx >> 3, slot = idx & 7;
    const int c = slot ^ (row & 7);
    wgp[p] = (const char*)wt + (size_t)(n0 + row) * 9216 + (c << 4);
  }
  char* const wl = ldsW[0] + tid * 16;  // + buf*16384 + p*4096

  floatx4 accA[4][4] = {};              // P0 panel (even output rows)
  floatx4 accB[4][4] = {};              // P1 panel (odd output rows)

  // fragment row/site indices
  int arow[4], bsite[4];
#pragma unroll
  for (int f = 0; f < 4; ++f) arow[f] = wn + (f << 4) + ri;
#pragma unroll
  for (int fj = 0; fj < 4; ++fj)
    bsite[fj] = ((wm >> 5) + (fj >> 1)) * 34 + ((fj & 1) << 4) + ri;

  // flat W-tile schedule: taps 0..5 for both panels, 6..8 P0-only
  constexpr int NT = 15;
  constexpr int tapof[NT] = {0, 0, 1, 1, 2, 2, 3, 3, 4, 4, 5, 5, 6, 7, 8};
  constexpr int pof[NT]   = {0, 1, 0, 1, 0, 1, 0, 1, 0, 1, 0, 1, 0, 0, 0};

  for (int chunk = 0; chunk < 8; ++chunk) {
    const int cb = chunk << 7;
    // ---- chunk prologue: X | fence | tile0 | fence | tile1 ----
    // (all LDS readers of the previous chunk returned before its final
    //  WAITBAR0, which drained vm+lgkm to 0.)
#pragma unroll
    for (int p = 0; p < 6; ++p) ASYNC16(xgp[p] + cb, xlp[p]);
    if (tid < 96) ASYNC16(xgp[6] + cb, xlp[6]);   // tail: 1632 = 6*256+96
    ISSUE_FENCE;   // X emitted before tile0 (vmcnt counts emission order)
#pragma unroll
    for (int p = 0; p < 4; ++p) ASYNC16(wgp[p] + cb, wl + p * 4096);
    ISSUE_FENCE;   // tile0 before tile1 -> "newest 4" at the wait == tile1
#pragma unroll
    for (int p = 0; p < 4; ++p)
      ASYNC16(wgp[p] + WPAN + cb, wl + 16384 + p * 4096);
    WAITBAR4;                            // X + tile0 landed; tile1 in flight
#pragma unroll
    for (int i = 0; i < NT; ++i) {
      // prefetch tile i+2 into buf[(i+2)%3] (its readers were segment i-1;
      // their ds_reads RETURNED before segment i-1's fused barrier)
      if (i + 2 < NT) {
        const size_t noff =
            (size_t)(pof[i + 2] ? WPAN : 0u) + (tapof[i + 2] << 10) + cb;
        char* const wld = ldsW[0] + ((i + 2) % 3) * 16384 + tid * 16;
#pragma unroll
        for (int p = 0; p < 4; ++p) ASYNC16(wgp[p] + noff, wld + p * 4096);
      }
      const char* wb = ldsW[0] + (i % 3) * 16384;
      const int tsite = (tapof[i] / 3) * 34 + (tapof[i] % 3);
      if (pof[i] == 0)
        mfma_seg(wb, ldsX, arow, bsite, tsite, kg, accA);
      else
        mfma_seg(wb, ldsX, arow, bsite, tsite, kg, accB);
      // tile i+1 resident for next segment (vmcnt<=4); own ds_reads all
      // returned (lgkmcnt 0); tile i+2 crosses the barrier in flight.
      if (i + 2 < NT) { WAITBAR4; } else { WAITBAR0; }
    }
  }

  // ---- epilogue: +bias, dense 2x2 pixel-shuffle writes, fused BN stats ----
  // D layout: col=lane&15 (m), row=quad*4+reg (n). Pair-interleaved rows:
  // (j0,j1) = co (cols 2w/2w+1), (j2,j3) = co+1. accA -> row 2h (P0),
  // accB -> row 2h+1 (P1). Stats for co combine both parities (atomics /2).
  const int quad = kg, colL = ri;
#pragma unroll
  for (int fi = 0; fi < 4; ++fi) {
    const int rbase = n0 + wn + (fi << 4) + (quad << 2);   // P0 row', j=0..3
    const floatx4 bvA = *(const floatx4*)(bias + rbase);
    const floatx4 bvB = *(const floatx4*)(bias + 512 + rbase);
    const int co = rbase >> 1;
    float s0 = 0.f, q0 = 0.f, s1 = 0.f, q1 = 0.f;
    float* ob = out + (((size_t)(n_img * 256 + co)) << 12);
#pragma unroll
    for (int fj = 0; fj < 4; ++fj) {
      const int mb = wm + (fj << 4) + colL;       // m within block
      const int h = h0p + (mb >> 5), w = mb & 31; // global h (0..31)
      const float vA0 = accA[fi][fj][0] + bvA[0];
      const float vA1 = accA[fi][fj][1] + bvA[1];
      const float vA2 = accA[fi][fj][2] + bvA[2];
      const float vA3 = accA[fi][fj][3] + bvA[3];
      const float vB0 = accB[fi][fj][0] + bvB[0];
      const float vB1 = accB[fi][fj][1] + bvB[1];
      const float vB2 = accB[fi][fj][2] + bvB[2];
      const float vB3 = accB[fi][fj][3] + bvB[3];
      s0 += (vA0 + vA1) + (vB0 + vB1);
      q0 += vA0 * vA0 + vA1 * vA1 + vB0 * vB0 + vB1 * vB1;
      s1 += (vA2 + vA3) + (vB2 + vB3);
      q1 += vA2 * vA2 + vA3 * vA3 + vB2 * vB2 + vB3 * vB3;
      float* p = ob + (h << 7) + (w << 1);        // row 2h, col 2w
      floatx2 eA0 = {vA0, vA1};
      floatx2 eB0 = {vB0, vB1};
      floatx2 eA1 = {vA2, vA3};
      floatx2 eB1 = {vB2, vB3};
      *(floatx2*)p = eA0;                          // co,   row 2h
      *(floatx2*)(p + 64) = eB0;                   // co,   row 2h+1
      *(floatx2*)(p + 4096) = eA1;                 // co+1, row 2h
      *(floatx2*)(p + 4160) = eB1;                 // co+1, row 2h+1
    }
#pragma unroll
    for (int off = 1; off < 16; off <<= 1) {
      s0 += __shfl_xor(s0, off);
      q0 += __shfl_xor(q0, off);
      s1 += __shfl_xor(s1, off);
      q1 += __shfl_xor(q1, off);
    }
    if (colL == 0) {
      atomicAdd(&stats[co], s0);
      atomicAdd(&stats[256 + co], q0);
      atomicAdd(&stats[co + 1], s1);
      atomicAdd(&stats[256 + co + 1], q1);
    }
  }
}

// -------------------------------------------------------------- bn_apply ---
__global__ __launch_bounds__(256) void bn_apply(
    float* __restrict__ y, const float* __restrict__ stats,
    const float* __restrict__ gamma, const float* __restrict__ beta) {
  const int b = blockIdx.x;
  const int co = b & 255;
  const int t = threadIdx.x;
  const float mean = stats[co] * (1.f / 65536.f);
  const float var = stats[256 + co] * (1.f / 65536.f) - mean * mean;
  const float rstd = rsqrtf(var + 1e-5f);
  const float scale = rstd * gamma[co];
  const float shift = beta[co] - mean * scale;
  float* p = y + (size_t)b * 4096;
#pragma unroll
  for (int it = 0; it < 4; ++it) {
    floatx4* q = (floatx4*)(p + (it * 256 + t) * 4);
    floatx4 v = *q;
#pragma unroll
    for (int e = 0; e < 4; ++e) v[e] = fmaxf(v[e] * scale + shift, 0.f);
    *q = v;
  }
}

// ---------------------------------------------------------------- launch ---
extern "C" void kernel_launch(void* const* d_in, const int* in_sizes, int n_in,
                              void* d_out, int out_size, void* d_ws,
                              size_t ws_size, hipStream_t stream) {
  const float* x  = (const float*)d_in[0];
  const float* w1 = (const float*)d_in[1];
  const float* b1 = (const float*)d_in[2];
  const float* w2 = (const float*)d_in[3];
  const float* b2 = (const float*)d_in[4];
  const float* w3 = (const float*)d_in[5];
  const float* b3 = (const float*)d_in[6];
  const float* w4 = (const float*)d_in[7];
  const float* b4 = (const float*)d_in[8];
  const float* gamma = (const float*)d_in[9];
  const float* beta  = (const float*)d_in[10];
  float* out = (float*)d_out;

  char* ws = (char*)d_ws;
  ushort_t* xt   = (ushort_t*)(ws + XT_OFF);
  ushort_t* wt   = (ushort_t*)(ws + WT_OFF);
  float*    bias = (float*)(ws + BIAS_OFF);
  float*    st   = (float*)(ws + STATS_OFF);

  prep_all<<<1568, 256, 0, stream>>>(x, xt, w1, w2, w3, w4,
                                     b1, b2, b3, b4, wt, bias, st);
  gemm_kernel<<<512, 256, 0, stream>>>(xt, wt, bias, out, st);
  bn_apply<<<4096, 256, 0, stream>>>(out, st, gamma, beta);
}

// Round 11
// 258.704 us; speedup vs baseline: 1.2391x; 1.2391x over previous
//
#include <hip/hip_runtime.h>
#include <hip/hip_bf16.h>

// FastUpConvolution on MI355X — round 18: gemm reverted VERBATIM to R16
// (verified 144us: counted-vmcnt triple-buffer pipeline, fused
// {vmcnt(4) lgkmcnt(0); s_barrier}); this round's single change is
// quarter-split X-prep: one block per (n, hp, ci-quarter) -> 2176 X blocks
// (was 544), ONE transpose round + ONE barrier per block (was 4 rounds /
// 8 barriers serial).
//
// R17 post-mortem: panel-pair fusion cut FETCH 82->68MB as predicted but
// OccupancyPercent 19.5->11.1 (~1 resident block/CU: 200 VGPR + identical
// phase-locked pipelines) -> every pipe idled, gemm 198us. Heterogeneous
// (9-tap+6-tap) 2-block co-residency of R16 was doing real latency hiding.
// Reverted. Non-gemm side is ~120us of the 264 total vs ~40us ideal memory
// time -> prep parallelism is the diagnosable sink.
//
// ws layout:
//   x_t   : bf16 [16][34][34][512]  @ 0          (18,939,904 B)
//   W_t   : bf16 [1024 rows][9*512] @ 18,939,904 ( 9,437,184 B)  row=pair-ilv
//   bias  : f32  [1024]             @ 28,377,088 (     4,096 B)  row=pair-ilv
//   stats : f32  [512] sum|sumsq    @ 28,381,184 (     2,048 B)
//
// Row layout: row' = ((q&1)<<9) + co*2 + (q>>1):
//   P0 rows 0..511   : q0 (3x3) s=0, q2 (3x2) s=1  -> even output rows, 9 taps
//   P1 rows 512..1023: q1 (2x3) s=0, q3 (2x2) s=1  -> odd output rows, 6 taps

typedef unsigned short ushort_t;
typedef __attribute__((ext_vector_type(8))) short short8;
typedef __attribute__((ext_vector_type(4))) float floatx4;
typedef __attribute__((ext_vector_type(2))) float floatx2;
typedef __attribute__((ext_vector_type(4))) unsigned short u16x4;
typedef __attribute__((ext_vector_type(8))) unsigned short u16x8;
typedef __attribute__((ext_vector_type(4))) unsigned int u32x4;

#define XT_OFF    0u
#define WT_OFF    18939904u
#define BIAS_OFF  28377088u
#define STATS_OFF 28381184u

#define NSITES_P0 204         // 6 rows x 34 cols X footprint, 128 B per site
#define NSITES_P1 170         // 5 rows x 34 cols (taps 0..5 only)

#define ASYNC16(g, l) __builtin_amdgcn_global_load_lds( \
    (const __attribute__((address_space(1))) void*)(g), \
    (__attribute__((address_space(3))) void*)(l), 16, 0, 0)

// Zero-instruction compiler fence: pins emission order of memory intrinsics
// (vmcnt counts in emission order; counted waits depend on it).
#define ISSUE_FENCE asm volatile("" ::: "memory")

// Fused wait+barrier (R16-proven). vmcnt(4): own W prefetch stays in flight.
// lgkmcnt(0): all own LDS reads returned before the barrier (no WAR vs the
// next segment's DMA into the recycled buffer).
#define WAITBAR4 \
  asm volatile("s_waitcnt vmcnt(4) lgkmcnt(0)\n\ts_barrier" ::: "memory")
#define WAITBAR0 \
  asm volatile("s_waitcnt vmcnt(0) lgkmcnt(0)\n\ts_barrier" ::: "memory")

__device__ __forceinline__ ushort_t f2bf(float f) {
  unsigned int u = __builtin_bit_cast(unsigned int, f);
  u += 0x7fffu + ((u >> 16) & 1u);   // RNE (values finite here)
  return (ushort_t)(u >> 16);
}

// --------------------------------------------------------------- prep_all --
// Blocks 0..1023: W prep (block 0 also zeroes stats).
// Blocks 1024..3199: X prep, one block per (n, hp, ci-quarter):
//   x[16][512][32][32] f32 -> x_t[16][34][34][512] bf16, zero-padded NHWC.
//   One 128-ci transpose round, one barrier.
__global__ __launch_bounds__(256) void prep_all(
    const float* __restrict__ x, ushort_t* __restrict__ xt,
    const float* __restrict__ w1, const float* __restrict__ w2,
    const float* __restrict__ w3, const float* __restrict__ w4,
    const float* __restrict__ b1, const float* __restrict__ b2,
    const float* __restrict__ b3, const float* __restrict__ b4,
    ushort_t* __restrict__ wt, float* __restrict__ bias,
    float* __restrict__ stats) {
  __shared__ ushort_t lds[128 * 36];   // 9,216 B
  const int blk = blockIdx.x;
  const int t = threadIdx.x;
  if (blk < 1024) {
    // ---------------- W prep ----------------
    const int q = blk >> 8, co = blk & 255;
    const int row = ((q & 1) << 9) + (co << 1) + (q >> 1);  // pair-interleaved
    if (blk == 0) { stats[t] = 0.f; stats[t + 256] = 0.f; }
    const float* wsrc; const float* bsrc; int khl, kwl;
    if (q == 0)      { wsrc = w1; bsrc = b1; khl = 3; kwl = 3; }
    else if (q == 1) { wsrc = w2; bsrc = b2; khl = 2; kwl = 3; }
    else if (q == 2) { wsrc = w3; bsrc = b3; khl = 3; kwl = 2; }
    else             { wsrc = w4; bsrc = b4; khl = 2; kwl = 2; }
    if (t == 0) bias[row] = bsrc[co];
    ushort_t* dst = wt + (size_t)row * 4608;
    for (int tap = 0; tap < 9; ++tap) {
      const int dh = tap / 3, dw = tap % 3;
      const bool valid = (dh < khl) && (dw < kwl);
#pragma unroll
      for (int cc = 0; cc < 2; ++cc) {
        const int ci = cc * 256 + t;
        ushort_t v = 0;
        if (valid)
          v = f2bf(wsrc[(((size_t)co * 512 + ci) * khl + dh) * kwl + dw]);
        dst[tap * 512 + ci] = v;
      }
    }
    return;
  }
  // ---------------- X prep (quarter) ----------------
  const int idx = blk - 1024;
  const int n = idx / 136;            // 136 = 34 hp * 4 quarters
  const int rem = idx % 136;
  const int hp = rem >> 2;
  const int ci0 = (rem & 3) << 7;     // 0,128,256,384
  ushort_t* dst = xt + (size_t)(n * 34 + hp) * (34 * 512);
  if (hp == 0 || hp == 33) {
    // zero this quarter's 34 w-positions x 128 ci: 544 u32x4
    u32x4 z = {0u, 0u, 0u, 0u};
    for (int i = t; i < 544; i += 256)
      ((u32x4*)(dst + (i >> 4) * 512 + ci0))[i & 15] = z;
    return;
  }
  const int h = hp - 1;
  // zero pads at w=0 and w=33 for this ci slice (2 x 16 u32x4)
  if (t < 32) {
    u32x4 z = {0u, 0u, 0u, 0u};
    const int w = (t >> 4) ? 33 : 0;
    ((u32x4*)(dst + w * 512 + ci0))[t & 15] = z;
  }
  // load 128 ci x 32 w f32, convert, transpose via LDS, store bf16 NHWC
  const size_t base = (size_t)n * 524288 + (size_t)h * 32;
  {
    const int cil = t >> 3;
    const int w4 = (t & 7) << 2;
#pragma unroll
    for (int cc = 0; cc < 4; ++cc) {
      const int ci = cil + cc * 32;
      floatx4 v = *(const floatx4*)(x + base + (size_t)(ci0 + ci) * 1024 + w4);
      u16x4 hv;
#pragma unroll
      for (int j = 0; j < 4; ++j) hv[j] = f2bf(v[j]);
      *(u16x4*)&lds[ci * 36 + w4] = hv;
    }
  }
  __syncthreads();
  {
    const int w = t & 31;
    const int j8 = t >> 5;
#pragma unroll
    for (int cc2 = 0; cc2 < 2; ++cc2) {
      const int cil2 = cc2 * 64 + j8 * 8;
      u16x8 v;
#pragma unroll
      for (int j = 0; j < 8; ++j) v[j] = lds[(cil2 + j) * 36 + w];
      *(u16x8*)(dst + (w + 1) * 512 + ci0 + cil2) = v;
    }
  }
}

// ------------------------------------------------------------- gemm body ---
// (VERBATIM R16.) Block 128 m (4h x 32w) x 128 n (one quadrant-pair);
// 4 waves 2x2, 4x4 frags of 16x16x32 bf16. K = 8 chunks x 64 ci x NTAPS
// (compile-time: P0 9, P1 6). Per chunk: stage X | fence | W0->wb0 | fence |
// W1->wb1, fused {vmcnt(4) lgkm(0); barrier}. Per tap t: issue W(t+2) into
// wb[(t+2)%3]; 2 k-steps x 16 MFMA on wb[t%3]; fused wait+bar.
// LDS unpadded, XOR-swizzled: 16B chunk c of row r at slot c^(r&7).
template <int NTAPS, int NSITES_T>
__device__ __forceinline__ void gemm_body(
    const ushort_t* __restrict__ xt, const ushort_t* __restrict__ wt,
    const float* __restrict__ bias, float* __restrict__ out,
    float* __restrict__ stats, char* ldsX, char* ldsW,
    int bn, int bm) {
  const int tid = threadIdx.x;
  const int n0 = bn << 7;
  const int n_img = bm >> 3;
  const int h0p = (bm & 7) << 2;        // first padded x_t row of footprint
  const int wv = tid >> 6, lane = tid & 63;
  const int ri = lane & 15, kg = lane >> 4;
  const int wm = (wv & 1) << 6, wn = (wv >> 1) << 6;

  constexpr int XTOT = NSITES_T * 8;    // 16B loads for X footprint
  constexpr int XFP = XTOT / 256;       // full 256-thread passes
  constexpr int XTL = XTOT - XFP * 256; // tail threads

  // ---- staging pointer precompute (XOR swizzle at issue) ----
  const char* xgp[XFP + 1];
  char* xlp[XFP + 1];
  {
    const char* xg = (const char*)(xt + (size_t)(n_img * 34 + h0p) * (34 * 512));
#pragma unroll
    for (int p = 0; p < XFP + 1; ++p) {
      const int idx = p * 256 + tid;
      const int site = idx >> 3, slot = idx & 7;
      const int c = slot ^ (site & 7);
      xgp[p] = xg + site * 1024 + (c << 4);
      xlp[p] = ldsX + idx * 16;
    }
  }
  // W: idx = p*256+tid over 1024 = 128 rows x 8 slots; 3 LDS buffers.
  const char* wgp[4];
#pragma unroll
  for (int p = 0; p < 4; ++p) {
    const int idx = p * 256 + tid;
    const int row = idx >> 3, slot = idx & 7;
    const int c = slot ^ (row & 7);
    wgp[p] = (const char*)wt + (size_t)(n0 + row) * 9216 + (c << 4);
  }
  char* const wl = ldsW + tid * 16;     // + buf*16384 + p*4096

  floatx4 acc[4][4] = {};

  // fragment row/site indices
  int arow[4], bsite[4];
#pragma unroll
  for (int f = 0; f < 4; ++f) arow[f] = wn + (f << 4) + ri;
#pragma unroll
  for (int fj = 0; fj < 4; ++fj)
    bsite[fj] = ((wm >> 5) + (fj >> 1)) * 34 + ((fj & 1) << 4) + ri;

  for (int chunk = 0; chunk < 8; ++chunk) {
    const int cb = chunk << 7;
    // ---- chunk prologue: stage X | fence | W0 | fence | W1 ----
    // (ldsX / wb0 / wb1 readers all finished — data returned — before the
    //  last-tap barrier of the previous chunk, which drained vm+lgkm to 0.)
#pragma unroll
    for (int p = 0; p < XFP; ++p) ASYNC16(xgp[p] + cb, xlp[p]);
    if (tid < XTL) ASYNC16(xgp[XFP] + cb, xlp[XFP]);   // tail
    ISSUE_FENCE;   // X emitted before W0 (vmcnt counts in emission order)
#pragma unroll
    for (int p = 0; p < 4; ++p) ASYNC16(wgp[p] + cb, wl + p * 4096);
    ISSUE_FENCE;   // W0 emitted before W1 -> "newest 4" at the wait == W1
#pragma unroll
    for (int p = 0; p < 4; ++p)
      ASYNC16(wgp[p] + cb + 1024, wl + 16384 + p * 4096);
    WAITBAR4;                            // X + W0 landed; W1's 4 in flight
#pragma unroll
    for (int tap = 0; tap < NTAPS; ++tap) {
      // prefetch W(tap+2) into wb[(tap+2)%3] (readers of that buffer were
      // tap-1; their ds_reads RETURNED before tap-1's fused barrier)
      if (tap + 2 < NTAPS) {
        const int noff = ((tap + 2) << 10) + cb;
        char* const wld = ldsW + ((tap + 2) % 3) * 16384 + tid * 16;
#pragma unroll
        for (int p = 0; p < 4; ++p) ASYNC16(wgp[p] + noff, wld + p * 4096);
      }
      const char* wb = ldsW + (tap % 3) * 16384;
      const int tsite = (tap / 3) * 34 + (tap % 3);   // X site offset of tap
#pragma unroll
      for (int ks = 0; ks < 2; ++ks) {
        const int c = (ks << 2) + kg;    // 16B chunk index within row
        short8 a4[4], b4[4];
#pragma unroll
        for (int f = 0; f < 4; ++f)
          a4[f] = *(const short8*)(wb + arow[f] * 128 +
                                   ((c ^ (arow[f] & 7)) << 4));
#pragma unroll
        for (int fj = 0; fj < 4; ++fj) {
          const int srow = bsite[fj] + tsite;   // shifted site; swizzle on it
          b4[fj] = *(const short8*)(ldsX + srow * 128 + ((c ^ (srow & 7)) << 4));
        }
#pragma unroll
        for (int fi = 0; fi < 4; ++fi)
#pragma unroll
          for (int fj = 0; fj < 4; ++fj)
            acc[fi][fj] = __builtin_amdgcn_mfma_f32_16x16x32_bf16(
                a4[fi], b4[fj], acc[fi][fj], 0, 0, 0);
      }
      // end-of-tap sync: W(tap+1) resident for next tap (vmcnt<=4); own
      // ds_reads all returned (lgkmcnt 0); W(tap+2) crosses in flight.
      if (tap + 2 < NTAPS) { WAITBAR4; } else { WAITBAR0; }
    }
  }

  // ---- epilogue: +bias, dense 2x2 pixel-shuffle writes, fused BN stats ----
  // D layout: col=lane&15 (m), row=quad*4+reg (n). Pair-interleaved rows:
  // (j0,j1) = same co, cols 2w/2w+1 -> contiguous floatx2; (j2,j3) = co+1.
  // Output row parity: P0 (bn<4) -> even rows; P1 -> odd rows.
  const int quad = kg, colL = ri;
  const int dh6 = (bn >> 2) << 6;       // +64 floats for odd output rows
#pragma unroll
  for (int fi = 0; fi < 4; ++fi) {
    const int rbase = n0 + wn + (fi << 4) + (quad << 2);   // global row', j=0..3
    const floatx4 bv = *(const floatx4*)(bias + rbase);
    const int co = (rbase & 511) >> 1;
    float sA = 0.f, s2A = 0.f, sB = 0.f, s2B = 0.f;
    float* ob = out + (((size_t)(n_img * 256 + co)) << 12) + dh6;
#pragma unroll
    for (int fj = 0; fj < 4; ++fj) {
      const int mb = wm + (fj << 4) + colL;       // m within block
      const int h = h0p + (mb >> 5), w = mb & 31; // global h (0..31)
      const float v0 = acc[fi][fj][0] + bv[0];
      const float v1 = acc[fi][fj][1] + bv[1];
      const float v2 = acc[fi][fj][2] + bv[2];
      const float v3 = acc[fi][fj][3] + bv[3];
      sA += v0 + v1;
      s2A += v0 * v0 + v1 * v1;
      sB += v2 + v3;
      s2B += v2 * v2 + v3 * v3;
      float* p = ob + (h << 7) + (w << 1);        // row 2h(+dh), col 2w
      floatx2 eA = {v0, v1};
      floatx2 eB = {v2, v3};
      *(floatx2*)p = eA;                           // co
      *(floatx2*)(p + 4096) = eB;                  // co+1
    }
#pragma unroll
    for (int off = 1; off < 16; off <<= 1) {
      sA += __shfl_xor(sA, off);
      s2A += __shfl_xor(s2A, off);
      sB += __shfl_xor(sB, off);
      s2B += __shfl_xor(s2B, off);
    }
    if (colL == 0) {
      atomicAdd(&stats[co], sA);
      atomicAdd(&stats[256 + co], s2A);
      atomicAdd(&stats[co + 1], sB);
      atomicAdd(&stats[256 + co + 1], s2B);
    }
  }
}

__global__ __launch_bounds__(256) void gemm_kernel(
    const ushort_t* __restrict__ xt, const ushort_t* __restrict__ wt,
    const float* __restrict__ bias, float* __restrict__ out,
    float* __restrict__ stats) {
  // LDS declared once, shared by both instantiations (75,264 B total
  // -> still 2 blocks/CU).
  __shared__ char ldsX[NSITES_P0 * 128]; // 26,112 B
  __shared__ char ldsW[3][128 * 128];    // 3 x 16,384 B (triple buffer)
  const int bx = blockIdx.x;
  // Panel flip at the grid midpoint: each XCD (bx&7 under round-robin
  // dispatch) runs 64 blocks of panel k, then 64 of panel k^4 -> per-XCD
  // 9-tap/6-tap totals balanced; <=2 W panels live per XCD L2.
  const int bn = (bx & 7) ^ (((bx >> 9) & 1) << 2);
  const int bm = (bx >> 3) & 127;
  if (bn < 4)
    gemm_body<9, NSITES_P0>(xt, wt, bias, out, stats,
                            ldsX, ldsW[0], bn, bm);
  else
    gemm_body<6, NSITES_P1>(xt, wt, bias, out, stats,
                            ldsX, ldsW[0], bn, bm);
}

// -------------------------------------------------------------- bn_apply ---
__global__ __launch_bounds__(256) void bn_apply(
    float* __restrict__ y, const float* __restrict__ stats,
    const float* __restrict__ gamma, const float* __restrict__ beta) {
  const int b = blockIdx.x;
  const int co = b & 255;
  const int t = threadIdx.x;
  const float mean = stats[co] * (1.f / 65536.f);
  const float var = stats[256 + co] * (1.f / 65536.f) - mean * mean;
  const float rstd = rsqrtf(var + 1e-5f);
  const float scale = rstd * gamma[co];
  const float shift = beta[co] - mean * scale;
  float* p = y + (size_t)b * 4096;
#pragma unroll
  for (int it = 0; it < 4; ++it) {
    floatx4* q = (floatx4*)(p + (it * 256 + t) * 4);
    floatx4 v = *q;
#pragma unroll
    for (int e = 0; e < 4; ++e) v[e] = fmaxf(v[e] * scale + shift, 0.f);
    *q = v;
  }
}

// ---------------------------------------------------------------- launch ---
extern "C" void kernel_launch(void* const* d_in, const int* in_sizes, int n_in,
                              void* d_out, int out_size, void* d_ws,
                              size_t ws_size, hipStream_t stream) {
  const float* x  = (const float*)d_in[0];
  const float* w1 = (const float*)d_in[1];
  const float* b1 = (const float*)d_in[2];
  const float* w2 = (const float*)d_in[3];
  const float* b2 = (const float*)d_in[4];
  const float* w3 = (const float*)d_in[5];
  const float* b3 = (const float*)d_in[6];
  const float* w4 = (const float*)d_in[7];
  const float* b4 = (const float*)d_in[8];
  const float* gamma = (const float*)d_in[9];
  const float* beta  = (const float*)d_in[10];
  float* out = (float*)d_out;

  char* ws = (char*)d_ws;
  ushort_t* xt   = (ushort_t*)(ws + XT_OFF);
  ushort_t* wt   = (ushort_t*)(ws + WT_OFF);
  float*    bias = (float*)(ws + BIAS_OFF);
  float*    st   = (float*)(ws + STATS_OFF);

  prep_all<<<3200, 256, 0, stream>>>(x, xt, w1, w2, w3, w4,
                                     b1, b2, b3, b4, wt, bias, st);
  gemm_kernel<<<1024, 256, 0, stream>>>(xt, wt, bias, out, st);
  bn_apply<<<4096, 256, 0, stream>>>(out, st, gamma, beta);
}